// Round 11
// baseline (150.520 us; speedup 1.0000x reference)
//
#include <hip/hip_runtime.h>
#include <math.h>

#define BATCH 32
#define CIN   256
#define LEN   8192
#define HL    (LEN/2)
#define ORD   8
#define NPOS  (BATCH*LEN)   // 262144 positions

struct Params { const float* p[32]; };

// Input index map (setup_inputs dict order):
// 0 x, 1 conv1_w, 2 conv1_b, 3 conv2_b
// w_ branch: 4 c1w, 5 c1b, 6 c2w, 7 c2b, 8 g1, 9 g2, 10 g3, 11 b1, 12 b2,
//            13 b3, 14 pxw, 15 pxb, 16 fcw, 17 fcb        (c_ branch = +14)
// ws: [0:32) conv sum  [32:64) conv sumsq  [64:80) cpre sum  [80:96) cpre sumsq
//     [96:608) per-sample c sums: 96 + br*256 + b*8 + ch
// ws+1024: cpre[16][NPOS] (16.8 MB scratch)

__device__ __forceinline__ void wave_reduce2(float& sv, float& sq)
{
#pragma unroll
    for (int m = 32; m >= 1; m >>= 1) {
        sv += __shfl_xor(sv, m, 64);
        sq += __shfl_xor(sq, m, 64);
    }
}
__device__ __forceinline__ void wave_reduce1(float& sv)
{
#pragma unroll
    for (int m = 32; m >= 1; m >>= 1) sv += __shfl_xor(sv, m, 64);
}

// conv weights staged in LDS: wl[(bc*8+o)*24 + i*3 + k]   (256-thread version)
__device__ __forceinline__ void load_conv_lds(const Params& P, float* wl, float* bl, int tid)
{
    for (int idx = tid; idx < 4*192; idx += 256) {
        int which = idx / 192, s = idx - which*192;
        const float* src = (which==0) ? P.p[4] : (which==1) ? P.p[6]
                         : (which==2) ? P.p[18] : P.p[20];
        wl[idx] = src[s];
    }
    if (tid < 32) {
        int wq = tid >> 3, o = tid & 7;
        const float* bsrc = (wq==0) ? P.p[5] : (wq==1) ? P.p[7]
                          : (wq==2) ? P.p[19] : P.p[21];
        bl[tid] = bsrc[o];
    }
}

// conv pre-act pair (positions p, p+1); one 24-weight LDS fetch shared by
// both positions. row = bc*8+o, dil compile-time.
__device__ __forceinline__ void conv6_pair_lds(
    const float xv[8][6], const float* wl, float bv, int dil, int row,
    float& r0, float& r1)
{
    float a0 = bv, a1 = bv;
    const float4* wr4 = reinterpret_cast<const float4*>(wl + row*24);
    float wr[24];
#pragma unroll
    for (int q = 0; q < 6; q++) *reinterpret_cast<float4*>(&wr[4*q]) = wr4[q];
#pragma unroll
    for (int i = 0; i < 8; i++) {
        float w0 = wr[i*3+0], w1 = wr[i*3+1], w2 = wr[i*3+2];
        if (dil == 1) {
            a0 += w0*xv[i][1] + w1*xv[i][2] + w2*xv[i][3];
            a1 += w0*xv[i][2] + w1*xv[i][3] + w2*xv[i][4];
        } else {
            a0 += w0*xv[i][0] + w1*xv[i][2] + w2*xv[i][4];
            a1 += w0*xv[i][1] + w1*xv[i][3] + w2*xv[i][5];
        }
    }
    r0 = a0; r1 = a1;
}

#define XT_W 264   // k3 tile: 2 pad + 2 halo + 256 interior + 2 halo + 2 pad
#define LOAD_XV6(xt, tp, xv)                                  \
    _Pragma("unroll")                                         \
    for (int i_ = 0; i_ < 8; i_++) {                          \
        _Pragma("unroll")                                     \
        for (int d_ = 0; d_ < 6; d_++)                        \
            xv[i_][d_] = xt[i_][2 + 2*(tp) + d_];             \
    }

// stage x1 tile [t0-2, t0+258) into xt (interior at offset 4)
__device__ __forceinline__ void stage_tile256(
    const float* __restrict__ x1, int b, int t0, float (*xt)[XT_W], int tid)
{
    int ch = tid >> 5, q = tid & 31;
    const float* src = x1 + ((size_t)b*ORD + ch)*LEN + t0;
    float4 a0 = *reinterpret_cast<const float4*>(src + q*8);
    float4 a1 = *reinterpret_cast<const float4*>(src + q*8 + 4);
    *reinterpret_cast<float4*>(&xt[ch][4 + q*8]) = a0;
    *reinterpret_cast<float4*>(&xt[ch][8 + q*8]) = a1;
    if (tid < 32) {
        int hc = tid >> 2, hh = tid & 3;
        int l   = t0 + ((hh < 2) ? (hh - 2) : (254 + hh));   // -2,-1,256,257
        int idx = (hh < 2) ? (2 + hh) : (258 + hh);          // 2,3,260,261
        xt[hc][idx] = ((unsigned)l < (unsigned)LEN)
                    ? x1[((size_t)b*ORD + hc)*LEN + l] : 0.f;
    }
}

// ---------------------------------------------------------------------------
// K1 v4: 128 blocks x 1024 threads, tile = 2048 positions (float2/thread).
// Each block reads 8 KB CONTIGUOUS per input row per visit (32K row visits
// total vs 65K at tile=1024). BW still saturated: 128 resident CUs x ~170
// GB/s in-flight capability >> 6.3 TB/s HBM. Fused bn1/bn2 stats.
// ---------------------------------------------------------------------------
#define XT1_W 2056   // 2 pad + 2 halo + 2048 interior + 2 halo + 2 pad
__global__ __launch_bounds__(1024, 4) void k1_gemm_stats(
    const float* __restrict__ x, const float* __restrict__ w,
    const float* __restrict__ bias, float* __restrict__ x1,
    float* __restrict__ ws, Params P)
{
    __shared__ float wt[CIN][ORD];     // conv1 weights wt[i][o]
    __shared__ float xt[ORD][XT1_W];   // x1 tile (65.8 KB)
    __shared__ float hbuf[4][257];     // halo x columns
    __shared__ float wl[768], bl[32];
    __shared__ float part[1024];
    int tid = threadIdx.x;
    for (int idx = tid; idx < CIN*ORD; idx += 1024) {
        int o = idx >> 8, i = idx & 255;          // source layout [o][i]
        wt[i][o] = w[idx];
    }
    if (tid < 768) {
        int which = tid / 192, s = tid - which*192;
        const float* src = (which==0) ? P.p[4] : (which==1) ? P.p[6]
                         : (which==2) ? P.p[18] : P.p[20];
        wl[tid] = src[s];
    }
    if (tid >= 768 && tid < 800) {
        int q = tid - 768, wq = q >> 3, o = q & 7;
        const float* bsrc = (wq==0) ? P.p[5] : (wq==1) ? P.p[7]
                          : (wq==2) ? P.p[19] : P.p[21];
        bl[q] = bsrc[o];
    }

    int b  = blockIdx.x >> 2;                     // 4 blocks per sample
    int t0 = (blockIdx.x & 3) << 11;              // 2048 positions per block

    // halo-x prefetch (threads 0-255, one channel each; latency hidden)
    float h0 = 0.f, h1 = 0.f, h2 = 0.f, h3 = 0.f;
    if (tid < 256) {
        const float* xch = x + ((size_t)b*CIN + tid)*LEN;
        if (t0 >= 2)         { h0 = xch[t0-2];    h1 = xch[t0-1]; }
        if (t0 + 2049 < LEN) { h2 = xch[t0+2048]; h3 = xch[t0+2049]; }
    }
    __syncthreads();                              // wt ready

    // main stream: thread owns float2 at position t0+2*tid
    const float2* xrow = reinterpret_cast<const float2*>(x + (size_t)b*CIN*LEN + t0) + tid;
    float2 acc[ORD];
#pragma unroll
    for (int o = 0; o < ORD; o++) { acc[o].x = 0.f; acc[o].y = 0.f; }

#pragma unroll 8
    for (int i = 0; i < CIN; i++) {
        float2 xv2 = xrow[(size_t)i * HL];
        const float4* wr = reinterpret_cast<const float4*>(&wt[i][0]);
        float4 wa = wr[0], wb = wr[1];
        acc[0].x += xv2.x*wa.x; acc[0].y += xv2.y*wa.x;
        acc[1].x += xv2.x*wa.y; acc[1].y += xv2.y*wa.y;
        acc[2].x += xv2.x*wa.z; acc[2].y += xv2.y*wa.z;
        acc[3].x += xv2.x*wa.w; acc[3].y += xv2.y*wa.w;
        acc[4].x += xv2.x*wb.x; acc[4].y += xv2.y*wb.x;
        acc[5].x += xv2.x*wb.y; acc[5].y += xv2.y*wb.y;
        acc[6].x += xv2.x*wb.z; acc[6].y += xv2.y*wb.z;
        acc[7].x += xv2.x*wb.w; acc[7].y += xv2.y*wb.w;
    }

    float2* x1b = reinterpret_cast<float2*>(x1 + (size_t)b*ORD*LEN + t0) + tid;
#pragma unroll
    for (int o = 0; o < ORD; o++) {
        float bo = bias[o];
        float2 r; r.x = acc[o].x + bo; r.y = acc[o].y + bo;
        x1b[(size_t)o * HL] = r;
        *reinterpret_cast<float2*>(&xt[o][4 + 2*tid]) = r;
    }
    if (tid < 256) {
        hbuf[0][tid] = h0; hbuf[1][tid] = h1; hbuf[2][tid] = h2; hbuf[3][tid] = h3;
    }
    __syncthreads();

    // halo x1 (-2,-1,2048,2049) from LDS-held x columns
    if (tid < 32) {
        int hq = tid >> 3, ch = tid & 7;
        int l  = t0 + ((hq < 2) ? (hq - 2) : (2046 + hq));
        float a = 0.f;
        if ((unsigned)l < (unsigned)LEN) {
            a = bias[ch];
#pragma unroll 8
            for (int i = 0; i < CIN; i++) a += hbuf[hq][i] * wt[i][ch];
        }
        int idx = (hq < 2) ? (2 + hq) : (2050 + hq);   // 2,3,2052,2053
        xt[ch][idx] = a;
    }
    __syncthreads();

    // stats tail: thread handles position pair (2*tid, 2*tid+1); 16 waves
    {
        float xv[8][6];
        LOAD_XV6(xt, tid, xv);
        int lane = tid & 63, wv = tid >> 6;       // wv in [0,16)
#pragma unroll
        for (int grp = 0; grp < 4; grp++) {
#pragma unroll
            for (int o = 0; o < 8; o++) {
                int c = grp*8 + o;
                float a0, a1;
                if (grp & 1) conv6_pair_lds(xv, wl, bl[c], 2, c, a0, a1);
                else         conv6_pair_lds(xv, wl, bl[c], 1, c, a0, a1);
                float sv = a0 + a1, sq = a0*a0 + a1*a1;
                wave_reduce2(sv, sq);
                if (lane == 0) { part[c*16 + wv] = sv; part[512 + c*16 + wv] = sq; }
            }
        }
    }
    __syncthreads();
    if (tid < 64) {
        const float* pp = &part[(tid < 32) ? tid*16 : 512 + (tid-32)*16];
        float s = 0.f;
#pragma unroll
        for (int q = 0; q < 16; q++) s += pp[q];
        atomicAdd(&ws[tid], s);
    }
}

// ---------------------------------------------------------------------------
// K3: bn1/bn2+relu, pointwise conv -> c_pre (materialized); bn3 stats
// 1024 blocks, tile 256; 2 positions/thread, branch split across halves.
// ---------------------------------------------------------------------------
__global__ __launch_bounds__(256, 4) void k3_cpre_stats(
    const float* __restrict__ x1, float* __restrict__ ws,
    float* __restrict__ cpre, Params P)
{
    __shared__ float wl[768], bl[32];
    __shared__ float pxl[128], pxbl[16];
    __shared__ float scl[32], shf[32];
    __shared__ float xt[ORD][XT_W];
    __shared__ float part[64];
    int tid = threadIdx.x;
    load_conv_lds(P, wl, bl, tid);
    if (tid >= 128) { int q = tid - 128; pxl[q] = (q < 64) ? P.p[14][q] : P.p[28][q-64]; }
    if (tid >= 112 && tid < 128) { int q = tid - 112; pxbl[q] = (q < 8) ? P.p[15][q] : P.p[29][q-8]; }
    if (tid >= 32 && tid < 64) {
        int c = tid - 32;
        int br = c >> 4, cv = (c >> 3) & 1, o = c & 7;
        const float Ninv = 1.0f / (float)NPOS;
        float m   = ws[c]      * Ninv;
        float var = ws[32 + c] * Ninv - m*m;
        const float* g  = P.p[ br ? (cv?23:22) : (cv?9:8)  ];
        const float* be = P.p[ br ? (cv?26:25) : (cv?12:11)];
        float sc = g[o] * rsqrtf(var + 1e-5f);
        scl[c] = sc; shf[c] = be[o] - m*sc;
    }
    int b  = blockIdx.x >> 5;
    int t0 = (blockIdx.x & 31) << 8;
    stage_tile256(x1, b, t0, xt, tid);
    __syncthreads();

    const int tp = tid & 127;          // position pair (2*tp, 2*tp+1)
    const int br = tid >> 7;           // branch handled by this half
    float xv[8][6];
    LOAD_XV6(xt, tp, xv);

    int lane = tid & 63, wv = tid >> 6;
    float s0[8], s1[8];
#pragma unroll
    for (int ch = 0; ch < 8; ch++) {
        int ca = (br*2+0)*8 + ch, cb = (br*2+1)*8 + ch;
        float a0, a1, c0, c1;
        conv6_pair_lds(xv, wl, bl[ca], 1, ca, a0, a1);
        conv6_pair_lds(xv, wl, bl[cb], 2, cb, c0, c1);
        s0[ch] = fmaxf(a0*scl[ca] + shf[ca], 0.f) + fmaxf(c0*scl[cb] + shf[cb], 0.f);
        s1[ch] = fmaxf(a1*scl[ca] + shf[ca], 0.f) + fmaxf(c1*scl[cb] + shf[cb], 0.f);
    }
#pragma unroll
    for (int o = 0; o < 8; o++) {
        float a0 = pxbl[br*8 + o], a1 = a0;
#pragma unroll
        for (int i = 0; i < 8; i++) {
            a0 += pxl[br*64 + o*8 + i] * s0[i];
            a1 += pxl[br*64 + o*8 + i] * s1[i];
        }
        int c = br*8 + o;
        float2 st; st.x = a0; st.y = a1;
        *reinterpret_cast<float2*>(
            &cpre[(size_t)c*NPOS + (size_t)b*LEN + t0 + 2*tp]) = st;
        float sv = a0 + a1, sq = a0*a0 + a1*a1;
        wave_reduce2(sv, sq);
        if (lane == 0) {
            part[c*2 + (wv&1)]        = sv;   // c in [0,16)
            part[32 + c*2 + (wv&1)]   = sq;
        }
    }
    __syncthreads();
    if (tid < 32) {
        float s = part[tid*2] + part[tid*2+1];
        atomicAdd(&ws[64 + tid], s);
    }
}

// ---------------------------------------------------------------------------
// K4: light pass over c_pre -> relu(bn3) -> per-sample channel sums
// ---------------------------------------------------------------------------
__global__ __launch_bounds__(256) void k4_light(
    const float* __restrict__ cpre, float* __restrict__ ws, Params P)
{
    __shared__ float scl3[16], shf3[16];
    __shared__ float part[64];
    int tid = threadIdx.x;
    const float Ninv = 1.0f / (float)NPOS;
    if (tid < 16) {
        int br = tid >> 3, o = tid & 7;
        float m3 = ws[64 + tid] * Ninv;
        float v3 = ws[80 + tid] * Ninv - m3*m3;
        const float* g3 = P.p[ br ? 24 : 10 ];
        const float* b3 = P.p[ br ? 27 : 13 ];
        float sc = g3[o] * rsqrtf(v3 + 1e-5f);
        scl3[tid] = sc; shf3[tid] = b3[o] - m3*sc;
    }
    __syncthreads();

    int b  = blockIdx.x >> 4;
    int t0 = (blockIdx.x & 15) << 9;
    int lane = tid & 63, wv = tid >> 6;
#pragma unroll
    for (int c = 0; c < 16; c++) {
        float2 v = *reinterpret_cast<const float2*>(
            &cpre[(size_t)c*NPOS + (size_t)b*LEN + t0 + 2*tid]);
        float sv = fmaxf(v.x*scl3[c] + shf3[c], 0.f)
                 + fmaxf(v.y*scl3[c] + shf3[c], 0.f);
        wave_reduce1(sv);
        if (lane == 0) part[c*4 + wv] = sv;
    }
    __syncthreads();
    if (tid < 16) {
        float s = part[tid*4] + part[tid*4+1] + part[tid*4+2] + part[tid*4+3];
        atomicAdd(&ws[96 + (tid >> 3)*256 + b*8 + (tid & 7)], s);
    }
}

// ---------------------------------------------------------------------------
// K6: fc -> width/center -> Hermite kernel (parallel over k) -> 8x9 conv
// ---------------------------------------------------------------------------
#define XT6_W 272
__global__ __launch_bounds__(256) void k6_out(
    const float* __restrict__ x1, const float* __restrict__ ws, Params P,
    float* __restrict__ out)
{
    __shared__ float kern[8][9];
    __shared__ float xt[8][XT6_W];
    int tid = threadIdx.x;
    int b  = blockIdx.x >> 5;
    int t0 = (blockIdx.x & 31) << 8;

    {   // vectorized stage: interior at offset 8, halo 4 each side
        int ch = tid >> 5, q = tid & 31;
        const float* src = x1 + ((size_t)b*ORD + ch)*LEN + t0;
        float4 a0 = *reinterpret_cast<const float4*>(src + q*8);
        float4 a1 = *reinterpret_cast<const float4*>(src + q*8 + 4);
        *reinterpret_cast<float4*>(&xt[ch][8  + q*8]) = a0;
        *reinterpret_cast<float4*>(&xt[ch][12 + q*8]) = a1;
        if (q < 4) {                   // left: l = t0-4+q -> xt[4+q]
            int l = t0 - 4 + q;
            xt[ch][4 + q] = (l >= 0) ? src[q - 4] : 0.f;
        } else if (q < 8) {            // right: l = t0+256+(q-4) -> xt[260+q]
            int l = t0 + 256 + (q - 4);
            xt[ch][260 + q] = (l < LEN) ? src[256 + q - 4] : 0.f;
        }
    }

    if (tid < 9) {
        // each of 9 threads: fc (redundant) + its own k column
        const float Li = 1.0f / (float)LEN;
        float vw = P.p[17][0], vc = P.p[31][0];
#pragma unroll
        for (int ch = 0; ch < 8; ch++) {
            vw += P.p[16][ch] * (ws[96 +       b*8 + ch] * Li);
            vc += P.p[30][ch] * (ws[96 + 256 + b*8 + ch] * Li);
        }
        float width  = vw;
        float center = fminf(fmaxf(vc, 1.0f), 128.0f);

        float cst[7];
        cst[0] = 0.56418958354775628f;            // 1/sqrt(pi)
#pragma unroll
        for (int i = 1; i < 7; i++) cst[i] = cst[i-1] * sqrtf(2.0f / (float)i);

        int k = tid;
        float t = width * ((float)k - center);
        float e = expf(-0.5f * t * t);
        float hp = 1.0f, hc = 2.0f * t;
        kern[0][k] = e * cst[0];
        kern[1][k] = e * cst[1] * hc;
#pragma unroll
        for (int i = 2; i < 7; i++) {
            float hn = 2.0f*t*hc - 2.0f*(float)(i-1)*hp;
            hp = hc; hc = hn;
            kern[i][k] = e * cst[i] * hc;
        }
        kern[7][k] = 1.0f / (1.0f + expf(-2.0f * t));
    }
    __syncthreads();
    if (tid < 7) {                     // normalize rows 0..6 over k
        float ss = 0.f;
#pragma unroll
        for (int k = 0; k < 9; k++) ss += kern[tid][k]*kern[tid][k];
        float inv = 1.0f / fmaxf(sqrtf(ss), 1e-12f);
#pragma unroll
        for (int k = 0; k < 9; k++) kern[tid][k] *= inv;
    }
    __syncthreads();

    float acc = P.p[3][0];
#pragma unroll
    for (int c = 0; c < 8; c++) {
#pragma unroll
        for (int j = 0; j < 9; j++) acc += xt[c][4 + tid + j] * kern[c][j];
    }
    out[(size_t)b*LEN + t0 + tid] = acc;
}

// ---------------------------------------------------------------------------
extern "C" void kernel_launch(void* const* d_in, const int* in_sizes, int n_in,
                              void* d_out, int out_size, void* d_ws, size_t ws_size,
                              hipStream_t stream)
{
    (void)in_sizes; (void)n_in; (void)out_size; (void)ws_size;
    const float* x  = (const float*)d_in[0];
    const float* w1 = (const float*)d_in[1];
    const float* b1 = (const float*)d_in[2];
    float* outF = (float*)d_out;
    float* x1   = outF + (size_t)BATCH * LEN;   // second tuple output
    float* ws   = (float*)d_ws;
    float* cpre = ws + 1024;                    // 16 x NPOS floats (16.8 MB)

    Params P;
    for (int i = 0; i < 32; i++) P.p[i] = (const float*)d_in[i];

    hipMemsetAsync(d_ws, 0, 4096, stream);
    k1_gemm_stats<<<128,  1024, 0, stream>>>(x, w1, b1, x1, ws, P);
    k3_cpre_stats<<<1024, 256,  0, stream>>>(x1, ws, cpre, P);
    k4_light     <<<512,  256,  0, stream>>>(cpre, ws, P);
    k6_out       <<<1024, 256,  0, stream>>>(x1, ws, P, outF);
}

// Round 12
// 125.323 us; speedup vs baseline: 1.2011x; 1.2011x over previous
//
#include <hip/hip_runtime.h>
#include <math.h>

#define BATCH 32
#define CIN   256
#define LEN   8192
#define HL    (LEN/2)
#define ORD   8
#define NPOS  (BATCH*LEN)   // 262144 positions

struct Params { const float* p[32]; };

// Input index map (setup_inputs dict order):
// 0 x, 1 conv1_w, 2 conv1_b, 3 conv2_b
// w_ branch: 4 c1w, 5 c1b, 6 c2w, 7 c2b, 8 g1, 9 g2, 10 g3, 11 b1, 12 b2,
//            13 b3, 14 pxw, 15 pxb, 16 fcw, 17 fcb        (c_ branch = +14)
// ws: [0:32) conv sum  [32:64) conv sumsq  [64:80) cpre sum  [80:96) cpre sumsq
//     [96:608) per-sample c sums: 96 + br*256 + b*8 + ch
// ws+1024: cpre[16][NPOS] (16.8 MB scratch)

__device__ __forceinline__ void wave_reduce2(float& sv, float& sq)
{
#pragma unroll
    for (int m = 32; m >= 1; m >>= 1) {
        sv += __shfl_xor(sv, m, 64);
        sq += __shfl_xor(sq, m, 64);
    }
}
__device__ __forceinline__ void wave_reduce1(float& sv)
{
#pragma unroll
    for (int m = 32; m >= 1; m >>= 1) sv += __shfl_xor(sv, m, 64);
}

// conv weights staged in LDS: wl[(bc*8+o)*24 + i*3 + k]   (256-thread version)
__device__ __forceinline__ void load_conv_lds(const Params& P, float* wl, float* bl, int tid)
{
    for (int idx = tid; idx < 4*192; idx += 256) {
        int which = idx / 192, s = idx - which*192;
        const float* src = (which==0) ? P.p[4] : (which==1) ? P.p[6]
                         : (which==2) ? P.p[18] : P.p[20];
        wl[idx] = src[s];
    }
    if (tid < 32) {
        int wq = tid >> 3, o = tid & 7;
        const float* bsrc = (wq==0) ? P.p[5] : (wq==1) ? P.p[7]
                          : (wq==2) ? P.p[19] : P.p[21];
        bl[tid] = bsrc[o];
    }
}

// conv pre-act pair (positions p, p+1); one 24-weight LDS fetch shared by
// both positions. row = bc*8+o, dil compile-time.
__device__ __forceinline__ void conv6_pair_lds(
    const float xv[8][6], const float* wl, float bv, int dil, int row,
    float& r0, float& r1)
{
    float a0 = bv, a1 = bv;
    const float4* wr4 = reinterpret_cast<const float4*>(wl + row*24);
    float wr[24];
#pragma unroll
    for (int q = 0; q < 6; q++) *reinterpret_cast<float4*>(&wr[4*q]) = wr4[q];
#pragma unroll
    for (int i = 0; i < 8; i++) {
        float w0 = wr[i*3+0], w1 = wr[i*3+1], w2 = wr[i*3+2];
        if (dil == 1) {
            a0 += w0*xv[i][1] + w1*xv[i][2] + w2*xv[i][3];
            a1 += w0*xv[i][2] + w1*xv[i][3] + w2*xv[i][4];
        } else {
            a0 += w0*xv[i][0] + w1*xv[i][2] + w2*xv[i][4];
            a1 += w0*xv[i][1] + w1*xv[i][3] + w2*xv[i][5];
        }
    }
    r0 = a0; r1 = a1;
}

#define XT_W 264   // k3 tile: 2 pad + 2 halo + 256 interior + 2 halo + 2 pad
#define LOAD_XV6(xt, tp, xv)                                  \
    _Pragma("unroll")                                         \
    for (int i_ = 0; i_ < 8; i_++) {                          \
        _Pragma("unroll")                                     \
        for (int d_ = 0; d_ < 6; d_++)                        \
            xv[i_][d_] = xt[i_][2 + 2*(tp) + d_];             \
    }

// stage x1 tile [t0-2, t0+258) into xt (interior at offset 4)
__device__ __forceinline__ void stage_tile256(
    const float* __restrict__ x1, int b, int t0, float (*xt)[XT_W], int tid)
{
    int ch = tid >> 5, q = tid & 31;
    const float* src = x1 + ((size_t)b*ORD + ch)*LEN + t0;
    float4 a0 = *reinterpret_cast<const float4*>(src + q*8);
    float4 a1 = *reinterpret_cast<const float4*>(src + q*8 + 4);
    *reinterpret_cast<float4*>(&xt[ch][4 + q*8]) = a0;
    *reinterpret_cast<float4*>(&xt[ch][8 + q*8]) = a1;
    if (tid < 32) {
        int hc = tid >> 2, hh = tid & 3;
        int l   = t0 + ((hh < 2) ? (hh - 2) : (254 + hh));   // -2,-1,256,257
        int idx = (hh < 2) ? (2 + hh) : (258 + hh);          // 2,3,260,261
        xt[hc][idx] = ((unsigned)l < (unsigned)LEN)
                    ? x1[((size_t)b*ORD + hc)*LEN + l] : 0.f;
    }
}

// ---------------------------------------------------------------------------
// K1 v5: 256 blocks x 1024 threads, tile = 1024 positions (r10 config) with
// the 256-channel stream CHUNKED (32 channels per chunk, barrier between) so
// all 16 waves visit the same 32-row x 4 KB window together -> fewer open
// DRAM rows at a time. Fused bn1/bn2 stats.
// ---------------------------------------------------------------------------
#define XT1_W 1036   // 2 pad + 2 halo + 1024 interior + 2 halo + pad
__global__ __launch_bounds__(1024, 4) void k1_gemm_stats(
    const float* __restrict__ x, const float* __restrict__ w,
    const float* __restrict__ bias, float* __restrict__ x1,
    float* __restrict__ ws, Params P)
{
    __shared__ float wt[CIN][ORD];     // conv1 weights wt[i][o]
    __shared__ float xt[ORD][XT1_W];   // x1 tile (33 KB)
    __shared__ float hbuf[4][257];     // halo x columns
    __shared__ float wl[768], bl[32];
    __shared__ float part[512];
    int tid = threadIdx.x;
    for (int idx = tid; idx < CIN*ORD; idx += 1024) {
        int o = idx >> 8, i = idx & 255;          // source layout [o][i]
        wt[i][o] = w[idx];
    }
    if (tid < 768) {
        int which = tid / 192, s = tid - which*192;
        const float* src = (which==0) ? P.p[4] : (which==1) ? P.p[6]
                         : (which==2) ? P.p[18] : P.p[20];
        wl[tid] = src[s];
    }
    if (tid >= 768 && tid < 800) {
        int q = tid - 768, wq = q >> 3, o = q & 7;
        const float* bsrc = (wq==0) ? P.p[5] : (wq==1) ? P.p[7]
                          : (wq==2) ? P.p[19] : P.p[21];
        bl[q] = bsrc[o];
    }

    int b  = blockIdx.x >> 3;                     // 8 blocks per sample
    int t0 = (blockIdx.x & 7) << 10;              // 1024 positions per block

    // halo-x prefetch (threads 0-255, one channel each; latency hidden)
    float h0 = 0.f, h1 = 0.f, h2 = 0.f, h3 = 0.f;
    if (tid < 256) {
        const float* xch = x + ((size_t)b*CIN + tid)*LEN;
        if (t0 >= 2)         { h0 = xch[t0-2];    h1 = xch[t0-1]; }
        if (t0 + 1025 < LEN) { h2 = xch[t0+1024]; h3 = xch[t0+1025]; }
    }
    __syncthreads();                              // wt ready

    // main stream: thread owns position t0+tid; per i, block reads 4 KB contig.
    // chunked i-loop keeps the block's 16 waves in the same 32-row window.
    const float* xrow = x + (size_t)b*CIN*LEN + t0 + tid;
    float acc[ORD];
#pragma unroll
    for (int o = 0; o < ORD; o++) acc[o] = 0.f;

    for (int ib = 0; ib < CIN; ib += 32) {
#pragma unroll 8
        for (int i = ib; i < ib + 32; i++) {
            float xv = xrow[(size_t)i * LEN];
            const float4* wr = reinterpret_cast<const float4*>(&wt[i][0]);
            float4 wa = wr[0], wb = wr[1];
            acc[0] += xv*wa.x; acc[1] += xv*wa.y; acc[2] += xv*wa.z; acc[3] += xv*wa.w;
            acc[4] += xv*wb.x; acc[5] += xv*wb.y; acc[6] += xv*wb.z; acc[7] += xv*wb.w;
        }
        __syncthreads();               // bound wave drift to this 32-row window
    }

    float* x1b = x1 + (size_t)b*ORD*LEN + t0 + tid;
#pragma unroll
    for (int o = 0; o < ORD; o++) {
        float r = acc[o] + bias[o];
        x1b[(size_t)o * LEN] = r;
        xt[o][4 + tid] = r;
    }
    if (tid < 256) {
        hbuf[0][tid] = h0; hbuf[1][tid] = h1; hbuf[2][tid] = h2; hbuf[3][tid] = h3;
    }
    __syncthreads();

    // halo x1 (-2,-1,1024,1025) from LDS-held x columns
    if (tid < 32) {
        int hq = tid >> 3, ch = tid & 7;
        int l  = t0 + ((hq < 2) ? (hq - 2) : (1022 + hq));
        float a = 0.f;
        if ((unsigned)l < (unsigned)LEN) {
            a = bias[ch];
#pragma unroll 8
            for (int i = 0; i < CIN; i++) a += hbuf[hq][i] * wt[i][ch];
        }
        int idx = (hq < 2) ? (2 + hq) : (1026 + hq);   // 2,3,1028,1029
        xt[ch][idx] = a;
    }
    __syncthreads();

    // stats tail: waves 0-7, thread tp handles position pair (2*tp, 2*tp+1)
    if (tid < 512) {
        int tp = tid;
        float xv[8][6];
        LOAD_XV6(xt, tp, xv);
        int lane = tid & 63, wv = tid >> 6;       // wv in [0,8)
#pragma unroll
        for (int grp = 0; grp < 4; grp++) {
#pragma unroll
            for (int o = 0; o < 8; o++) {
                int c = grp*8 + o;
                float a0, a1;
                if (grp & 1) conv6_pair_lds(xv, wl, bl[c], 2, c, a0, a1);
                else         conv6_pair_lds(xv, wl, bl[c], 1, c, a0, a1);
                float sv = a0 + a1, sq = a0*a0 + a1*a1;
                wave_reduce2(sv, sq);
                if (lane == 0) { part[c*8 + wv] = sv; part[256 + c*8 + wv] = sq; }
            }
        }
    }
    __syncthreads();
    if (tid < 64) {
        const float* pp = &part[(tid < 32) ? tid*8 : 256 + (tid-32)*8];
        float s = pp[0]+pp[1]+pp[2]+pp[3]+pp[4]+pp[5]+pp[6]+pp[7];
        atomicAdd(&ws[tid], s);
    }
}

// ---------------------------------------------------------------------------
// K3: bn1/bn2+relu, pointwise conv -> c_pre (materialized); bn3 stats
// 1024 blocks, tile 256; 2 positions/thread, branch split across halves.
// ---------------------------------------------------------------------------
__global__ __launch_bounds__(256, 4) void k3_cpre_stats(
    const float* __restrict__ x1, float* __restrict__ ws,
    float* __restrict__ cpre, Params P)
{
    __shared__ float wl[768], bl[32];
    __shared__ float pxl[128], pxbl[16];
    __shared__ float scl[32], shf[32];
    __shared__ float xt[ORD][XT_W];
    __shared__ float part[64];
    int tid = threadIdx.x;
    load_conv_lds(P, wl, bl, tid);
    if (tid >= 128) { int q = tid - 128; pxl[q] = (q < 64) ? P.p[14][q] : P.p[28][q-64]; }
    if (tid >= 112 && tid < 128) { int q = tid - 112; pxbl[q] = (q < 8) ? P.p[15][q] : P.p[29][q-8]; }
    if (tid >= 32 && tid < 64) {
        int c = tid - 32;
        int br = c >> 4, cv = (c >> 3) & 1, o = c & 7;
        const float Ninv = 1.0f / (float)NPOS;
        float m   = ws[c]      * Ninv;
        float var = ws[32 + c] * Ninv - m*m;
        const float* g  = P.p[ br ? (cv?23:22) : (cv?9:8)  ];
        const float* be = P.p[ br ? (cv?26:25) : (cv?12:11)];
        float sc = g[o] * rsqrtf(var + 1e-5f);
        scl[c] = sc; shf[c] = be[o] - m*sc;
    }
    int b  = blockIdx.x >> 5;
    int t0 = (blockIdx.x & 31) << 8;
    stage_tile256(x1, b, t0, xt, tid);
    __syncthreads();

    const int tp = tid & 127;          // position pair (2*tp, 2*tp+1)
    const int br = tid >> 7;           // branch handled by this half
    float xv[8][6];
    LOAD_XV6(xt, tp, xv);

    int lane = tid & 63, wv = tid >> 6;
    float s0[8], s1[8];
#pragma unroll
    for (int ch = 0; ch < 8; ch++) {
        int ca = (br*2+0)*8 + ch, cb = (br*2+1)*8 + ch;
        float a0, a1, c0, c1;
        conv6_pair_lds(xv, wl, bl[ca], 1, ca, a0, a1);
        conv6_pair_lds(xv, wl, bl[cb], 2, cb, c0, c1);
        s0[ch] = fmaxf(a0*scl[ca] + shf[ca], 0.f) + fmaxf(c0*scl[cb] + shf[cb], 0.f);
        s1[ch] = fmaxf(a1*scl[ca] + shf[ca], 0.f) + fmaxf(c1*scl[cb] + shf[cb], 0.f);
    }
#pragma unroll
    for (int o = 0; o < 8; o++) {
        float a0 = pxbl[br*8 + o], a1 = a0;
#pragma unroll
        for (int i = 0; i < 8; i++) {
            a0 += pxl[br*64 + o*8 + i] * s0[i];
            a1 += pxl[br*64 + o*8 + i] * s1[i];
        }
        int c = br*8 + o;
        float2 st; st.x = a0; st.y = a1;
        *reinterpret_cast<float2*>(
            &cpre[(size_t)c*NPOS + (size_t)b*LEN + t0 + 2*tp]) = st;
        float sv = a0 + a1, sq = a0*a0 + a1*a1;
        wave_reduce2(sv, sq);
        if (lane == 0) {
            part[c*2 + (wv&1)]        = sv;   // c in [0,16)
            part[32 + c*2 + (wv&1)]   = sq;
        }
    }
    __syncthreads();
    if (tid < 32) {
        float s = part[tid*2] + part[tid*2+1];
        atomicAdd(&ws[64 + tid], s);
    }
}

// ---------------------------------------------------------------------------
// K4: light pass over c_pre -> relu(bn3) -> per-sample channel sums
// ---------------------------------------------------------------------------
__global__ __launch_bounds__(256) void k4_light(
    const float* __restrict__ cpre, float* __restrict__ ws, Params P)
{
    __shared__ float scl3[16], shf3[16];
    __shared__ float part[64];
    int tid = threadIdx.x;
    const float Ninv = 1.0f / (float)NPOS;
    if (tid < 16) {
        int br = tid >> 3, o = tid & 7;
        float m3 = ws[64 + tid] * Ninv;
        float v3 = ws[80 + tid] * Ninv - m3*m3;
        const float* g3 = P.p[ br ? 24 : 10 ];
        const float* b3 = P.p[ br ? 27 : 13 ];
        float sc = g3[o] * rsqrtf(v3 + 1e-5f);
        scl3[tid] = sc; shf3[tid] = b3[o] - m3*sc;
    }
    __syncthreads();

    int b  = blockIdx.x >> 4;
    int t0 = (blockIdx.x & 15) << 9;
    int lane = tid & 63, wv = tid >> 6;
#pragma unroll
    for (int c = 0; c < 16; c++) {
        float2 v = *reinterpret_cast<const float2*>(
            &cpre[(size_t)c*NPOS + (size_t)b*LEN + t0 + 2*tid]);
        float sv = fmaxf(v.x*scl3[c] + shf3[c], 0.f)
                 + fmaxf(v.y*scl3[c] + shf3[c], 0.f);
        wave_reduce1(sv);
        if (lane == 0) part[c*4 + wv] = sv;
    }
    __syncthreads();
    if (tid < 16) {
        float s = part[tid*4] + part[tid*4+1] + part[tid*4+2] + part[tid*4+3];
        atomicAdd(&ws[96 + (tid >> 3)*256 + b*8 + (tid & 7)], s);
    }
}

// ---------------------------------------------------------------------------
// K6: fc -> width/center -> Hermite kernel (parallel over k) -> 8x9 conv
// ---------------------------------------------------------------------------
#define XT6_W 272
__global__ __launch_bounds__(256) void k6_out(
    const float* __restrict__ x1, const float* __restrict__ ws, Params P,
    float* __restrict__ out)
{
    __shared__ float kern[8][9];
    __shared__ float xt[8][XT6_W];
    int tid = threadIdx.x;
    int b  = blockIdx.x >> 5;
    int t0 = (blockIdx.x & 31) << 8;

    {   // vectorized stage: interior at offset 8, halo 4 each side
        int ch = tid >> 5, q = tid & 31;
        const float* src = x1 + ((size_t)b*ORD + ch)*LEN + t0;
        float4 a0 = *reinterpret_cast<const float4*>(src + q*8);
        float4 a1 = *reinterpret_cast<const float4*>(src + q*8 + 4);
        *reinterpret_cast<float4*>(&xt[ch][8  + q*8]) = a0;
        *reinterpret_cast<float4*>(&xt[ch][12 + q*8]) = a1;
        if (q < 4) {                   // left: l = t0-4+q -> xt[4+q]
            int l = t0 - 4 + q;
            xt[ch][4 + q] = (l >= 0) ? src[q - 4] : 0.f;
        } else if (q < 8) {            // right: l = t0+256+(q-4) -> xt[260+q]
            int l = t0 + 256 + (q - 4);
            xt[ch][260 + q] = (l < LEN) ? src[256 + q - 4] : 0.f;
        }
    }

    if (tid < 9) {
        // each of 9 threads: fc (redundant) + its own k column
        const float Li = 1.0f / (float)LEN;
        float vw = P.p[17][0], vc = P.p[31][0];
#pragma unroll
        for (int ch = 0; ch < 8; ch++) {
            vw += P.p[16][ch] * (ws[96 +       b*8 + ch] * Li);
            vc += P.p[30][ch] * (ws[96 + 256 + b*8 + ch] * Li);
        }
        float width  = vw;
        float center = fminf(fmaxf(vc, 1.0f), 128.0f);

        float cst[7];
        cst[0] = 0.56418958354775628f;            // 1/sqrt(pi)
#pragma unroll
        for (int i = 1; i < 7; i++) cst[i] = cst[i-1] * sqrtf(2.0f / (float)i);

        int k = tid;
        float t = width * ((float)k - center);
        float e = expf(-0.5f * t * t);
        float hp = 1.0f, hc = 2.0f * t;
        kern[0][k] = e * cst[0];
        kern[1][k] = e * cst[1] * hc;
#pragma unroll
        for (int i = 2; i < 7; i++) {
            float hn = 2.0f*t*hc - 2.0f*(float)(i-1)*hp;
            hp = hc; hc = hn;
            kern[i][k] = e * cst[i] * hc;
        }
        kern[7][k] = 1.0f / (1.0f + expf(-2.0f * t));
    }
    __syncthreads();
    if (tid < 7) {                     // normalize rows 0..6 over k
        float ss = 0.f;
#pragma unroll
        for (int k = 0; k < 9; k++) ss += kern[tid][k]*kern[tid][k];
        float inv = 1.0f / fmaxf(sqrtf(ss), 1e-12f);
#pragma unroll
        for (int k = 0; k < 9; k++) kern[tid][k] *= inv;
    }
    __syncthreads();

    float acc = P.p[3][0];
#pragma unroll
    for (int c = 0; c < 8; c++) {
#pragma unroll
        for (int j = 0; j < 9; j++) acc += xt[c][4 + tid + j] * kern[c][j];
    }
    out[(size_t)b*LEN + t0 + tid] = acc;
}

// ---------------------------------------------------------------------------
extern "C" void kernel_launch(void* const* d_in, const int* in_sizes, int n_in,
                              void* d_out, int out_size, void* d_ws, size_t ws_size,
                              hipStream_t stream)
{
    (void)in_sizes; (void)n_in; (void)out_size; (void)ws_size;
    const float* x  = (const float*)d_in[0];
    const float* w1 = (const float*)d_in[1];
    const float* b1 = (const float*)d_in[2];
    float* outF = (float*)d_out;
    float* x1   = outF + (size_t)BATCH * LEN;   // second tuple output
    float* ws   = (float*)d_ws;
    float* cpre = ws + 1024;                    // 16 x NPOS floats (16.8 MB)

    Params P;
    for (int i = 0; i < 32; i++) P.p[i] = (const float*)d_in[i];

    hipMemsetAsync(d_ws, 0, 4096, stream);
    k1_gemm_stats<<<256,  1024, 0, stream>>>(x, w1, b1, x1, ws, P);
    k3_cpre_stats<<<1024, 256,  0, stream>>>(x1, ws, cpre, P);
    k4_light     <<<512,  256,  0, stream>>>(cpre, ws, P);
    k6_out       <<<1024, 256,  0, stream>>>(x1, ws, P, outF);
}